// Round 5
// baseline (471.005 us; speedup 1.0000x reference)
//
#include <hip/hip_runtime.h>
#include <hip/hip_bf16.h>

#define NS 256    // n_state
#define MO 128    // n_obs
#define BB 64     // batch
#define TT 1024   // time steps

typedef short s16x8 __attribute__((ext_vector_type(8)));
typedef float f32x4 __attribute__((ext_vector_type(4)));
typedef unsigned int uint;
typedef unsigned short ushort;

__device__ __forceinline__ ushort f2bf(float x) {
    uint u = __float_as_uint(x);
    uint r = (u + 0x7fffu + ((u >> 16) & 1u)) >> 16;
    return (ushort)r;
}
__device__ __forceinline__ float bf2f(ushort h) { return __uint_as_float(((uint)h) << 16); }

__device__ __forceinline__ uint pkbf2(float a, float b) {
    __hip_bfloat162 h = __float22bfloat162_rn(make_float2(a, b));
    union { __hip_bfloat162 b2; uint u; } cv;
    cv.b2 = h;
    return cv.u;
}

// split 8 fp32 into bf16 hi + lo fragments (element order = k ascending)
__device__ __forceinline__ void conv8(float4 f0, float4 f1, s16x8& vh, s16x8& vl) {
    uint h0 = pkbf2(f0.x, f0.y), h1 = pkbf2(f0.z, f0.w);
    uint h2 = pkbf2(f1.x, f1.y), h3 = pkbf2(f1.z, f1.w);
    float r0 = f0.x - __uint_as_float(h0 << 16);
    float r1 = f0.y - __uint_as_float(h0 & 0xffff0000u);
    float r2 = f0.z - __uint_as_float(h1 << 16);
    float r3 = f0.w - __uint_as_float(h1 & 0xffff0000u);
    float r4 = f1.x - __uint_as_float(h2 << 16);
    float r5 = f1.y - __uint_as_float(h2 & 0xffff0000u);
    float r6 = f1.z - __uint_as_float(h3 << 16);
    float r7 = f1.w - __uint_as_float(h3 & 0xffff0000u);
    uint l0 = pkbf2(r0, r1), l1 = pkbf2(r2, r3);
    uint l2 = pkbf2(r4, r5), l3 = pkbf2(r6, r7);
    union { uint u[4]; s16x8 v; } ch, cl;
    ch.u[0] = h0; ch.u[1] = h1; ch.u[2] = h2; ch.u[3] = h3;
    cl.u[0] = l0; cl.u[1] = l1; cl.u[2] = l2; cl.u[3] = l3;
    vh = ch.v; vl = cl.v;
}

__device__ __forceinline__ f32x4 mfma16(s16x8 a, s16x8 b, f32x4 c) {
    return __builtin_amdgcn_mfma_f32_16x16x32_bf16(a, b, c, 0, 0, 0);
}

// ---------------- setup kernels ----------------

// KH = K @ H; also convert K -> kbh/kbl
__global__ void kh_kernel(const float* __restrict__ K, const float* __restrict__ H,
                          float* __restrict__ KH,
                          ushort* __restrict__ kbh, ushort* __restrict__ kbl) {
    int i = blockIdx.x, j = threadIdx.x;
    __shared__ float kl[MO];
    if (j < MO) {
        float v = K[i * MO + j];
        kl[j] = v;
        ushort hi = f2bf(v);
        kbh[i * MO + j] = hi;
        kbl[i * MO + j] = f2bf(v - bf2f(hi));
    }
    __syncthreads();
    float acc = 0.f;
#pragma unroll 8
    for (int k = 0; k < MO; ++k) acc += kl[k] * H[k * NS + j];
    KH[i * NS + j] = acc;
}

// AE = A - KH@A; also convert AE -> aeh/ael
__global__ void aeff_kernel(const float* __restrict__ A, const float* __restrict__ KH,
                            float* __restrict__ AE,
                            ushort* __restrict__ aeh, ushort* __restrict__ ael) {
    int i = blockIdx.x, j = threadIdx.x;
    __shared__ float khr[NS];
    khr[j] = KH[i * NS + j];
    __syncthreads();
    float acc = A[i * NS + j];
#pragma unroll 8
    for (int k = 0; k < NS; ++k) acc -= khr[k] * A[k * NS + j];
    AE[i * NS + j] = acc;
    ushort hi = f2bf(acc);
    aeh[i * NS + j] = hi;
    ael[i * NS + j] = f2bf(acc - bf2f(hi));
}

// dst = src@src; optional bf16 hi/lo conversion of dst
__global__ void matsq_kernel(const float* __restrict__ src, float* __restrict__ dst,
                             ushort* dh, ushort* dl) {
    int i = blockIdx.x, j = threadIdx.x;
    __shared__ float row[NS];
    row[j] = src[i * NS + j];
    __syncthreads();
    float acc = 0.f;
#pragma unroll 8
    for (int k = 0; k < NS; ++k) acc += row[k] * src[k * NS + j];
    dst[i * NS + j] = acc;
    if (dh) {
        ushort hi = f2bf(acc);
        dh[i * NS + j] = hi;
        dl[i * NS + j] = f2bf(acc - bf2f(hi));
    }
}

// ---------------- U = Y @ K^T (coalesced stores via LDS repack) ----------------
// grid 512, each block does 8 tiles of 16 rows. U written to d_out.

__launch_bounds__(512, 4)
__global__ void ugemm_kernel(const float* __restrict__ y, const ushort* __restrict__ kbh,
                             const ushort* __restrict__ kbl, float* __restrict__ U) {
    const int tid = threadIdx.x, blk = blockIdx.x;
    const int w = tid >> 6, l = tid & 63, lr = l & 15, lg = l >> 4;

    __shared__ float xe[16 * NS];

    s16x8 KBh[2][4], KBl[2][4];
#pragma unroll
    for (int t2 = 0; t2 < 2; ++t2) {
        int row = 16 * (2 * w + t2) + lr;
#pragma unroll
        for (int q = 0; q < 4; ++q) {
            int off = row * MO + 32 * q + 8 * lg;
            KBh[t2][q] = *(const s16x8*)(kbh + off);
            KBl[t2][q] = *(const s16x8*)(kbl + off);
        }
    }

#pragma unroll 1
    for (int it = 0; it < 8; ++it) {
        long row0 = ((long)blk * 8 + it) * 16;
        s16x8 Ah[4], Al[4];
#pragma unroll
        for (int q = 0; q < 4; ++q) {
            long off = (row0 + lr) * MO + 32 * q + 8 * lg;
            float4 f0 = *(const float4*)(y + off);
            float4 f1 = *(const float4*)(y + off + 4);
            conv8(f0, f1, Ah[q], Al[q]);
        }
        f32x4 acc0 = {0.f, 0.f, 0.f, 0.f};
        f32x4 acc1 = {0.f, 0.f, 0.f, 0.f};
#pragma unroll
        for (int q = 0; q < 4; ++q) {
            acc0 = mfma16(Ah[q], KBh[0][q], acc0);
            acc0 = mfma16(Al[q], KBh[0][q], acc0);
            acc0 = mfma16(Ah[q], KBl[0][q], acc0);
            acc1 = mfma16(Ah[q], KBh[1][q], acc1);
            acc1 = mfma16(Al[q], KBh[1][q], acc1);
            acc1 = mfma16(Ah[q], KBl[1][q], acc1);
        }
        const int col0 = 32 * w + lr, col1 = col0 + 16;
#pragma unroll
        for (int i = 0; i < 4; ++i) {
            int m = 4 * lg + i;
            xe[(m * NS + col0) ^ ((m & 7) << 2)] = acc0[i];
            xe[(m * NS + col1) ^ ((m & 7) << 2)] = acc1[i];
        }
        __syncthreads();
#pragma unroll
        for (int j = 0; j < 2; ++j) {
            int idx = j * 512 + tid;
            int r = idx >> 6;
            int wb = idx << 2;
            float4 v = *(const float4*)&xe[wb ^ ((r & 7) << 2)];
            *(float4*)(U + (row0 + r) * NS + (wb & 255)) = v;
        }
        __syncthreads();
    }
}

// ---------------- MFMA serial scan (one barrier/step, dbuf x-state) ----------------
// Hierarchy: 1024 = 8 (chunk) x 8 (group of chunks) x 16 (groups).
// MODE 0: grid 512, S=8, u=U fp32, x0=0, end -> e_buf (bf16).
// MODE 1: grid 64,  S=8, u=e_buf, x0=0, end -> e2 (bf16).
// MODE 2: grid 4,   S=15, u=e2, x0=0, writes c2[b,s+1], c2[b,0]=0.
// MODE 3: grid 64,  S=7, u=e_buf, x0=c2[b,g], writes cbuf[b,8g+s+1], cbuf[b,8g]=x0.
// MODE 4: grid 512, S=8, u=U fp32, x0=cbuf, writes out rows (LDS-repacked).

template <int MODE>
__launch_bounds__(512, 4)
__global__ void scan16_kernel(const ushort* __restrict__ mh, const ushort* __restrict__ ml,
                              const float* __restrict__ uf, const ushort* __restrict__ ub,
                              const ushort* __restrict__ cin, float* __restrict__ outf,
                              ushort* __restrict__ wbf, ushort* __restrict__ ebf) {
    constexpr int S = (MODE == 2) ? 15 : ((MODE == 3) ? 7 : 8);
    constexpr bool UF32 = (MODE == 0 || MODE == 4);
    const int tid = threadIdx.x, blk = blockIdx.x;
    const int w = tid >> 6, l = tid & 63, lr = l & 15, lg = l >> 4;

    __shared__ ushort xh_s[2][16 * NS];
    __shared__ ushort xl_s[2][16 * NS];
    __shared__ float xe_s[(MODE == 4) ? 2 * 16 * NS : 4];

    // ---- matrix fragments (bf16 hi/lo), 128 VGPR ----
    s16x8 Bh[2][8], Bl[2][8];
#pragma unroll
    for (int t2 = 0; t2 < 2; ++t2) {
        int row = 16 * (2 * w + t2) + lr;
#pragma unroll
        for (int q = 0; q < 8; ++q) {
            int off = row * NS + 32 * q + 8 * lg;
            Bh[t2][q] = *(const s16x8*)(mh + off);
            Bl[t2][q] = *(const s16x8*)(ml + off);
        }
    }

    // ---- init x state (buffer 0) + mode-specific init writes ----
#pragma unroll
    for (int jj = 0; jj < 8; ++jj) {
        int idx = jj * 512 + tid;  // 0..4095
        int m = idx >> 8, col = idx & 255;
        ushort hu = 0;
        if constexpr (MODE == 3) {
            int rid = blk * 16 + m;
            int b = rid >> 4, g = rid & 15;
            hu = cin[((long)b * 16 + g) * NS + col];
            wbf[((long)b * 128 + g * 8) * NS + col] = hu;  // carry into chunk 8g
        } else if constexpr (MODE == 4) {
            int b = (blk & 3) * 16 + m, cc = blk >> 2;
            hu = cin[((long)b * 128 + cc) * NS + col];
        } else if constexpr (MODE == 2) {
            int b = blk * 16 + m;
            wbf[(long)b * 16 * NS + col] = 0;  // c2[b,0] = 0
        }
        int si = (m * NS + col) ^ ((m & 7) << 3);
        xh_s[0][si] = hu;
        xl_s[0][si] = 0;
    }

    const int col0 = 32 * w + lr, col1 = col0 + 16;
    const int m0 = 4 * lg;

    // per-row u element-offset bases (step stride = NS)
    long ubo[4];
#pragma unroll
    for (int i = 0; i < 4; ++i) {
        int m = m0 + i;
        if constexpr (UF32) {
            int b = (blk & 3) * 16 + m, cc = blk >> 2;
            ubo[i] = ((long)b * TT + cc * 8) * NS;
        } else if constexpr (MODE == 1 || MODE == 3) {
            int rid = blk * 16 + m;
            ubo[i] = ((long)(rid >> 4) * 128 + (rid & 15) * 8) * NS;
        } else {
            ubo[i] = (long)(blk * 16 + m) * 16 * NS;
        }
    }

    // prefetch u(0)
    float up0[4], up1[4];
#pragma unroll
    for (int i = 0; i < 4; ++i) {
        if constexpr (UF32) {
            up0[i] = uf[ubo[i] + col0];
            up1[i] = uf[ubo[i] + col1];
        } else {
            up0[i] = bf2f(ub[ubo[i] + col0]);
            up1[i] = bf2f(ub[ubo[i] + col1]);
        }
    }
    __syncthreads();

    for (int s = 0; s < S; ++s) {
        const int cur = s & 1, nxt = cur ^ 1;
        f32x4 acc0, acc1;
        acc0[0] = up0[0]; acc0[1] = up0[1]; acc0[2] = up0[2]; acc0[3] = up0[3];
        acc1[0] = up1[0]; acc1[1] = up1[1]; acc1[2] = up1[2]; acc1[3] = up1[3];

#pragma unroll
        for (int q = 0; q < 8; ++q) {
            int ridx = (lr * NS + 32 * q + 8 * lg) ^ ((lr & 7) << 3);
            s16x8 xh = *(const s16x8*)&xh_s[cur][ridx];
            s16x8 xl = *(const s16x8*)&xl_s[cur][ridx];
            acc0 = mfma16(xh, Bh[0][q], acc0);
            acc0 = mfma16(xl, Bh[0][q], acc0);
            acc0 = mfma16(xh, Bl[0][q], acc0);
            acc1 = mfma16(xh, Bh[1][q], acc1);
            acc1 = mfma16(xl, Bh[1][q], acc1);
            acc1 = mfma16(xh, Bl[1][q], acc1);
        }

        // prefetch u(s+1)
        if (s + 1 < S) {
#pragma unroll
            for (int i = 0; i < 4; ++i) {
                long ue = ubo[i] + (long)(s + 1) * NS;
                if constexpr (UF32) {
                    up0[i] = uf[ue + col0];
                    up1[i] = uf[ue + col1];
                } else {
                    up0[i] = bf2f(ub[ue + col0]);
                    up1[i] = bf2f(ub[ue + col1]);
                }
            }
        }

        // mode-specific global stores
        if constexpr (MODE == 2) {
#pragma unroll
            for (int i = 0; i < 4; ++i) {
                int b = blk * 16 + m0 + i;
                long wb = ((long)b * 16 + s + 1) * NS;
                wbf[wb + col0] = f2bf(acc0[i]);
                wbf[wb + col1] = f2bf(acc1[i]);
            }
        } else if constexpr (MODE == 3) {
#pragma unroll
            for (int i = 0; i < 4; ++i) {
                int rid = blk * 16 + m0 + i;
                int b = rid >> 4, g = rid & 15;
                long wb = ((long)b * 128 + g * 8 + s + 1) * NS;
                wbf[wb + col0] = f2bf(acc0[i]);
                wbf[wb + col1] = f2bf(acc1[i]);
            }
        } else if constexpr (MODE == 0) {
            if (s == S - 1) {
#pragma unroll
                for (int i = 0; i < 4; ++i) {
                    int b = (blk & 3) * 16 + m0 + i, cc = blk >> 2;
                    long eb = ((long)b * 128 + cc) * NS;
                    ebf[eb + col0] = f2bf(acc0[i]);
                    ebf[eb + col1] = f2bf(acc1[i]);
                }
            }
        } else if constexpr (MODE == 1) {
            if (s == S - 1) {
#pragma unroll
                for (int i = 0; i < 4; ++i) {
                    int rid = blk * 16 + m0 + i;
                    long eb = ((long)(rid >> 4) * 16 + (rid & 15)) * NS;
                    ebf[eb + col0] = f2bf(acc0[i]);
                    ebf[eb + col1] = f2bf(acc1[i]);
                }
            }
        }

        // write x[nxt] (+ fp32 repack tile for mode 4)
#pragma unroll
        for (int i = 0; i < 4; ++i) {
            int m = m0 + i;
            {
                ushort hi = f2bf(acc0[i]);
                ushort lo = f2bf(acc0[i] - bf2f(hi));
                int wi = (m * NS + col0) ^ ((m & 7) << 3);
                xh_s[nxt][wi] = hi;
                xl_s[nxt][wi] = lo;
            }
            {
                ushort hi = f2bf(acc1[i]);
                ushort lo = f2bf(acc1[i] - bf2f(hi));
                int wi = (m * NS + col1) ^ ((m & 7) << 3);
                xh_s[nxt][wi] = hi;
                xl_s[nxt][wi] = lo;
            }
            if constexpr (MODE == 4) {
                xe_s[cur * 4096 + ((m * NS + col0) ^ ((m & 7) << 2))] = acc0[i];
                xe_s[cur * 4096 + ((m * NS + col1) ^ ((m & 7) << 2))] = acc1[i];
            }
        }
        __syncthreads();

        if constexpr (MODE == 4) {
            const int t = (blk >> 2) * 8 + s;
#pragma unroll
            for (int j = 0; j < 2; ++j) {
                int idx = j * 512 + tid;
                int r = idx >> 6;
                int wb = idx << 2;
                float4 v = *(const float4*)&xe_s[cur * 4096 + (wb ^ ((r & 7) << 2))];
                long ob = ((long)((blk & 3) * 16 + r) * TT + t) * NS + (wb & 255);
                *(float4*)(outf + ob) = v;
            }
        }
    }
}

// ---------------- launcher ----------------

extern "C" void kernel_launch(void* const* d_in, const int* in_sizes, int n_in,
                              void* d_out, int out_size, void* d_ws, size_t ws_size,
                              hipStream_t stream) {
    const float* y = (const float*)d_in[0];
    const float* A = (const float*)d_in[1];
    const float* H = (const float*)d_in[2];
    const float* K = (const float*)d_in[3];
    float* out = (float*)d_out;

    float* ws = (float*)d_ws;
    const long MAT = (long)NS * NS;  // 65536 floats
    float* KH = ws + 0 * MAT;
    float* AE = ws + 1 * MAT;
    float* Ta = ws + 2 * MAT;
    float* Tb = ws + 3 * MAT;
    float* M8 = ws + 4 * MAT;
    float* M64 = ws + 5 * MAT;
    ushort* aeh = (ushort*)(ws + 6 * MAT);
    ushort* ael = aeh + MAT;
    ushort* mh = (ushort*)(ws + 7 * MAT);
    ushort* ml = mh + MAT;
    ushort* m2h = (ushort*)(ws + 8 * MAT);
    ushort* m2l = m2h + MAT;
    ushort* kbh = (ushort*)(ws + 9 * MAT);
    ushort* kbl = kbh + (long)NS * MO;
    ushort* e_buf = (ushort*)(ws + 10 * MAT);  // [64][128][256] bf16 -> 16 MAT
    ushort* cbuf = (ushort*)(ws + 26 * MAT);   // [64][128][256] bf16 -> 16 MAT
    ushort* e2 = (ushort*)(ws + 42 * MAT);     // [64][16][256] bf16 -> 2 MAT
    ushort* c2 = (ushort*)(ws + 44 * MAT);     // [64][16][256] bf16 -> 2 MAT
    // total 46 MAT = 11.5 MB

    float* U = out;  // U = y@K^T lives in d_out; phase C overwrites in place

    kh_kernel<<<NS, NS, 0, stream>>>(K, H, KH, kbh, kbl);
    aeff_kernel<<<NS, NS, 0, stream>>>(A, KH, AE, aeh, ael);
    matsq_kernel<<<NS, NS, 0, stream>>>(AE, Ta, nullptr, nullptr);   // A^2
    matsq_kernel<<<NS, NS, 0, stream>>>(Ta, Tb, nullptr, nullptr);   // A^4
    matsq_kernel<<<NS, NS, 0, stream>>>(Tb, M8, mh, ml);             // A^8 (+conv)
    matsq_kernel<<<NS, NS, 0, stream>>>(M8, Ta, nullptr, nullptr);   // A^16
    matsq_kernel<<<NS, NS, 0, stream>>>(Ta, Tb, nullptr, nullptr);   // A^32
    matsq_kernel<<<NS, NS, 0, stream>>>(Tb, M64, m2h, m2l);          // A^64 (+conv)

    ugemm_kernel<<<512, 512, 0, stream>>>(y, kbh, kbl, U);

    scan16_kernel<0><<<512, 512, 0, stream>>>(aeh, ael, U, nullptr, nullptr, nullptr, nullptr, e_buf);
    scan16_kernel<1><<<64, 512, 0, stream>>>(mh, ml, nullptr, e_buf, nullptr, nullptr, nullptr, e2);
    scan16_kernel<2><<<4, 512, 0, stream>>>(m2h, m2l, nullptr, e2, nullptr, nullptr, c2, nullptr);
    scan16_kernel<3><<<64, 512, 0, stream>>>(mh, ml, nullptr, e_buf, c2, nullptr, cbuf, nullptr);
    scan16_kernel<4><<<512, 512, 0, stream>>>(aeh, ael, U, nullptr, cbuf, out, nullptr, nullptr);
}

// Round 6
// 259.329 us; speedup vs baseline: 1.8162x; 1.8162x over previous
//
#include <hip/hip_runtime.h>
#include <hip/hip_bf16.h>

#define NS 256    // n_state
#define MO 128    // n_obs
#define BB 64     // batch
#define TT 1024   // time steps

typedef short s16x8 __attribute__((ext_vector_type(8)));
typedef float f32x4 __attribute__((ext_vector_type(4)));
typedef unsigned int uint;
typedef unsigned short ushort;

__device__ __forceinline__ ushort f2bf(float x) {
    uint u = __float_as_uint(x);
    uint r = (u + 0x7fffu + ((u >> 16) & 1u)) >> 16;
    return (ushort)r;
}
__device__ __forceinline__ float bf2f(ushort h) { return __uint_as_float(((uint)h) << 16); }

__device__ __forceinline__ uint pkbf2(float a, float b) {
    __hip_bfloat162 h = __float22bfloat162_rn(make_float2(a, b));
    union { __hip_bfloat162 b2; uint u; } cv;
    cv.b2 = h;
    return cv.u;
}

// split 8 fp32 into bf16 hi + lo fragments (element order = k ascending)
__device__ __forceinline__ void conv8(float4 f0, float4 f1, s16x8& vh, s16x8& vl) {
    uint h0 = pkbf2(f0.x, f0.y), h1 = pkbf2(f0.z, f0.w);
    uint h2 = pkbf2(f1.x, f1.y), h3 = pkbf2(f1.z, f1.w);
    float r0 = f0.x - __uint_as_float(h0 << 16);
    float r1 = f0.y - __uint_as_float(h0 & 0xffff0000u);
    float r2 = f0.z - __uint_as_float(h1 << 16);
    float r3 = f0.w - __uint_as_float(h1 & 0xffff0000u);
    float r4 = f1.x - __uint_as_float(h2 << 16);
    float r5 = f1.y - __uint_as_float(h2 & 0xffff0000u);
    float r6 = f1.z - __uint_as_float(h3 << 16);
    float r7 = f1.w - __uint_as_float(h3 & 0xffff0000u);
    uint l0 = pkbf2(r0, r1), l1 = pkbf2(r2, r3);
    uint l2 = pkbf2(r4, r5), l3 = pkbf2(r6, r7);
    union { uint u[4]; s16x8 v; } ch, cl;
    ch.u[0] = h0; ch.u[1] = h1; ch.u[2] = h2; ch.u[3] = h3;
    cl.u[0] = l0; cl.u[1] = l1; cl.u[2] = l2; cl.u[3] = l3;
    vh = ch.v; vl = cl.v;
}

__device__ __forceinline__ f32x4 mfma16(s16x8 a, s16x8 b, f32x4 c) {
    return __builtin_amdgcn_mfma_f32_16x16x32_bf16(a, b, c, 0, 0, 0);
}

// ---------------- setup kernels ----------------

__global__ void kh_kernel(const float* __restrict__ K, const float* __restrict__ H,
                          float* __restrict__ KH,
                          ushort* __restrict__ kbh, ushort* __restrict__ kbl) {
    int i = blockIdx.x, j = threadIdx.x;
    __shared__ float kl[MO];
    if (j < MO) {
        float v = K[i * MO + j];
        kl[j] = v;
        ushort hi = f2bf(v);
        kbh[i * MO + j] = hi;
        kbl[i * MO + j] = f2bf(v - bf2f(hi));
    }
    __syncthreads();
    float acc = 0.f;
#pragma unroll 8
    for (int k = 0; k < MO; ++k) acc += kl[k] * H[k * NS + j];
    KH[i * NS + j] = acc;
}

__global__ void aeff_kernel(const float* __restrict__ A, const float* __restrict__ KH,
                            float* __restrict__ AE,
                            ushort* __restrict__ aeh, ushort* __restrict__ ael) {
    int i = blockIdx.x, j = threadIdx.x;
    __shared__ float khr[NS];
    khr[j] = KH[i * NS + j];
    __syncthreads();
    float acc = A[i * NS + j];
#pragma unroll 8
    for (int k = 0; k < NS; ++k) acc -= khr[k] * A[k * NS + j];
    AE[i * NS + j] = acc;
    ushort hi = f2bf(acc);
    aeh[i * NS + j] = hi;
    ael[i * NS + j] = f2bf(acc - bf2f(hi));
}

__global__ void matsq_kernel(const float* __restrict__ src, float* __restrict__ dst,
                             ushort* dh, ushort* dl) {
    int i = blockIdx.x, j = threadIdx.x;
    __shared__ float row[NS];
    row[j] = src[i * NS + j];
    __syncthreads();
    float acc = 0.f;
#pragma unroll 8
    for (int k = 0; k < NS; ++k) acc += row[k] * src[k * NS + j];
    dst[i * NS + j] = acc;
    if (dh) {
        ushort hi = f2bf(acc);
        dh[i * NS + j] = hi;
        dl[i * NS + j] = f2bf(acc - bf2f(hi));
    }
}

// ---------------- U = Y @ K^T (coalesced stores via LDS repack) ----------------

__launch_bounds__(512, 2)
__global__ void ugemm_kernel(const float* __restrict__ y, const ushort* __restrict__ kbh,
                             const ushort* __restrict__ kbl, float* __restrict__ U) {
    const int tid = threadIdx.x, blk = blockIdx.x;
    const int w = tid >> 6, l = tid & 63, lr = l & 15, lg = l >> 4;

    __shared__ float xe[16 * NS];

    s16x8 KBh[2][4], KBl[2][4];
#pragma unroll
    for (int t2 = 0; t2 < 2; ++t2) {
        int row = 16 * (2 * w + t2) + lr;
#pragma unroll
        for (int q = 0; q < 4; ++q) {
            int off = row * MO + 32 * q + 8 * lg;
            KBh[t2][q] = *(const s16x8*)(kbh + off);
            KBl[t2][q] = *(const s16x8*)(kbl + off);
        }
    }

#pragma unroll 1
    for (int it = 0; it < 8; ++it) {
        long row0 = ((long)blk * 8 + it) * 16;
        s16x8 Ah[4], Al[4];
#pragma unroll
        for (int q = 0; q < 4; ++q) {
            long off = (row0 + lr) * MO + 32 * q + 8 * lg;
            float4 f0 = *(const float4*)(y + off);
            float4 f1 = *(const float4*)(y + off + 4);
            conv8(f0, f1, Ah[q], Al[q]);
        }
        f32x4 acc0 = {0.f, 0.f, 0.f, 0.f};
        f32x4 acc1 = {0.f, 0.f, 0.f, 0.f};
#pragma unroll
        for (int q = 0; q < 4; ++q) {
            acc0 = mfma16(Ah[q], KBh[0][q], acc0);
            acc0 = mfma16(Al[q], KBh[0][q], acc0);
            acc0 = mfma16(Ah[q], KBl[0][q], acc0);
            acc1 = mfma16(Ah[q], KBh[1][q], acc1);
            acc1 = mfma16(Al[q], KBh[1][q], acc1);
            acc1 = mfma16(Ah[q], KBl[1][q], acc1);
        }
        const int col0 = 32 * w + lr, col1 = col0 + 16;
#pragma unroll
        for (int i = 0; i < 4; ++i) {
            int m = 4 * lg + i;
            xe[(m * NS + col0) ^ ((m & 7) << 2)] = acc0[i];
            xe[(m * NS + col1) ^ ((m & 7) << 2)] = acc1[i];
        }
        __syncthreads();
#pragma unroll
        for (int j = 0; j < 2; ++j) {
            int idx = j * 512 + tid;
            int r = idx >> 6;
            int wb = idx << 2;
            float4 v = *(const float4*)&xe[wb ^ ((r & 7) << 2)];
            *(float4*)(U + (row0 + r) * NS + (wb & 255)) = v;
        }
        __syncthreads();
    }
}

// ---------------- transposed MFMA serial scan ----------------
// D = M·x^T: matrix is the MFMA A-operand, x the B-operand. Each thread holds
// 4 consecutive out-states of one batch-column -> vector LDS writes (b64),
// vector u loads (float4 / uint2), direct float4 out stores.
// Hierarchy: 1024 = 8(step) x 8(chunk) x 16(group).
// MODE 0: grid 512, S=8, u=U fp32, x0=0, end -> e_buf bf16 [b][128][NS].
// MODE 1: grid 64,  S=8, u=e_buf (blk=b, lr=g), end -> e2 bf16 [b][16][NS].
// MODE 2: grid 4,   S=15, u=e2 (b=blk*16+lr), writes c2[b][s+1], c2[b][0]=0.
// MODE 3: grid 64,  S=7, u=e_buf, cin=c2, writes cbuf[b][8g+s+1], cbuf[b][8g]=cin.
// MODE 4: grid 512, S=8, u=U fp32, x0=cbuf[b][cc], writes out (float4 direct).

template <int MODE>
__launch_bounds__(512, 2)
__global__ void scan16_kernel(const ushort* __restrict__ mh, const ushort* __restrict__ ml,
                              const float* uf, const ushort* __restrict__ ub,
                              const ushort* __restrict__ cin, float* outf,
                              ushort* __restrict__ wbf, ushort* __restrict__ ebf) {
    constexpr int S = (MODE == 2) ? 15 : ((MODE == 3) ? 7 : 8);
    constexpr bool UF32 = (MODE == 0 || MODE == 4);
    const int tid = threadIdx.x, blk = blockIdx.x;
    const int w = tid >> 6, l = tid & 63, lr = l & 15, lg = l >> 4;

    __shared__ ushort xh_s[2][16 * NS];
    __shared__ ushort xl_s[2][16 * NS];

    // matrix A-fragments: lane holds M[32w+16t+lr][32q+8lg..+7] (hi/lo)
    s16x8 Bh[2][8], Bl[2][8];
#pragma unroll
    for (int t2 = 0; t2 < 2; ++t2) {
        int row = 16 * (2 * w + t2) + lr;
#pragma unroll
        for (int q = 0; q < 8; ++q) {
            int off = row * NS + 32 * q + 8 * lg;
            Bh[t2][q] = *(const s16x8*)(mh + off);
            Bl[t2][q] = *(const s16x8*)(ml + off);
        }
    }

    const int b0 = (blk & 3) * 16;   // modes 0/4
    const int cc = blk >> 2;         // modes 0/4

    // ---- init x state (buffer 0) + mode-specific init writes ----
#pragma unroll
    for (int jj = 0; jj < 8; ++jj) {
        int idx = jj * 512 + tid;  // 0..4095
        int m = idx >> 8, col = idx & 255;  // m = batch-column of tile
        ushort hu = 0;
        if constexpr (MODE == 3) {
            hu = cin[((long)blk * 16 + m) * NS + col];
            wbf[((long)blk * 128 + 8 * m) * NS + col] = hu;  // cbuf[b][8g] = carry
        } else if constexpr (MODE == 4) {
            hu = cin[((long)(b0 + m) * 128 + cc) * NS + col];
        } else if constexpr (MODE == 2) {
            wbf[((long)(blk * 16 + m) * 16) * NS + col] = 0;  // c2[b][0] = 0
        }
        int si = (m * NS + col) ^ ((m & 7) << 3);
        xh_s[0][si] = hu;
        xl_s[0][si] = 0;
    }

    // state-column bases for this thread's two tiles
    const int st0 = 32 * w + 4 * lg;
    const int st1 = st0 + 16;

    // u element-offset bases (step stride = NS)
    long ubase;
    if constexpr (UF32) {
        ubase = ((long)(b0 + lr) * TT + cc * 8) * NS;
    } else if constexpr (MODE == 1 || MODE == 3) {
        ubase = ((long)blk * 128 + 8 * lr) * NS;
    } else {
        ubase = ((long)(blk * 16 + lr) * 16) * NS;
    }

    auto ldu = [&](long off) -> f32x4 {
        if constexpr (UF32) {
            float4 v = *(const float4*)(uf + off);
            return f32x4{v.x, v.y, v.z, v.w};
        } else {
            uint2 v = *(const uint2*)(ub + off);
            return f32x4{__uint_as_float(v.x << 16), __uint_as_float(v.x & 0xffff0000u),
                         __uint_as_float(v.y << 16), __uint_as_float(v.y & 0xffff0000u)};
        }
    };

    f32x4 up0 = ldu(ubase + st0);
    f32x4 up1 = ldu(ubase + st1);
    __syncthreads();

    for (int s = 0; s < S; ++s) {
        const int cur = s & 1, nxt = cur ^ 1;
        f32x4 acc0 = up0, acc1 = up1;

#pragma unroll
        for (int q = 0; q < 8; ++q) {
            int ridx = (lr * NS + 32 * q + 8 * lg) ^ ((lr & 7) << 3);
            s16x8 xh = *(const s16x8*)&xh_s[cur][ridx];
            s16x8 xl = *(const s16x8*)&xl_s[cur][ridx];
            acc0 = mfma16(Bh[0][q], xh, acc0);
            acc0 = mfma16(Bh[0][q], xl, acc0);
            acc0 = mfma16(Bl[0][q], xh, acc0);
            acc1 = mfma16(Bh[1][q], xh, acc1);
            acc1 = mfma16(Bh[1][q], xl, acc1);
            acc1 = mfma16(Bl[1][q], xh, acc1);
        }

        // prefetch u(s+1)
        if (s + 1 < S) {
            up0 = ldu(ubase + (long)(s + 1) * NS + st0);
            up1 = ldu(ubase + (long)(s + 1) * NS + st1);
        }

        // packed bf16 of results (hi)
        uint h01a = pkbf2(acc0[0], acc0[1]), h23a = pkbf2(acc0[2], acc0[3]);
        uint h01b = pkbf2(acc1[0], acc1[1]), h23b = pkbf2(acc1[2], acc1[3]);

        // mode-specific global stores
        if constexpr (MODE == 2) {
            long wb = ((long)(blk * 16 + lr) * 16 + s + 1) * NS;
            *(uint2*)(wbf + wb + st0) = make_uint2(h01a, h23a);
            *(uint2*)(wbf + wb + st1) = make_uint2(h01b, h23b);
        } else if constexpr (MODE == 3) {
            long wb = ((long)blk * 128 + 8 * lr + s + 1) * NS;
            *(uint2*)(wbf + wb + st0) = make_uint2(h01a, h23a);
            *(uint2*)(wbf + wb + st1) = make_uint2(h01b, h23b);
        } else if constexpr (MODE == 4) {
            long ob = ((long)(b0 + lr) * TT + cc * 8 + s) * NS;
            *(f32x4*)(outf + ob + st0) = acc0;
            *(f32x4*)(outf + ob + st1) = acc1;
        } else if constexpr (MODE == 0) {
            if (s == S - 1) {
                long eb = ((long)(b0 + lr) * 128 + cc) * NS;
                *(uint2*)(ebf + eb + st0) = make_uint2(h01a, h23a);
                *(uint2*)(ebf + eb + st1) = make_uint2(h01b, h23b);
            }
        } else if constexpr (MODE == 1) {
            if (s == S - 1) {
                long eb = ((long)blk * 16 + lr) * NS;
                *(uint2*)(ebf + eb + st0) = make_uint2(h01a, h23a);
                *(uint2*)(ebf + eb + st1) = make_uint2(h01b, h23b);
            }
        }

        // write x[nxt]: 4 x ds_write_b64, conflict-free under (lr&7)<<3 XOR
        if (s + 1 < S) {
            float la0 = acc0[0] - __uint_as_float(h01a << 16);
            float la1 = acc0[1] - __uint_as_float(h01a & 0xffff0000u);
            float la2 = acc0[2] - __uint_as_float(h23a << 16);
            float la3 = acc0[3] - __uint_as_float(h23a & 0xffff0000u);
            float lb0 = acc1[0] - __uint_as_float(h01b << 16);
            float lb1 = acc1[1] - __uint_as_float(h01b & 0xffff0000u);
            float lb2 = acc1[2] - __uint_as_float(h23b << 16);
            float lb3 = acc1[3] - __uint_as_float(h23b & 0xffff0000u);
            int wi0 = lr * NS + (st0 ^ ((lr & 7) << 3));
            int wi1 = lr * NS + (st1 ^ ((lr & 7) << 3));
            *(uint2*)&xh_s[nxt][wi0] = make_uint2(h01a, h23a);
            *(uint2*)&xh_s[nxt][wi1] = make_uint2(h01b, h23b);
            *(uint2*)&xl_s[nxt][wi0] = make_uint2(pkbf2(la0, la1), pkbf2(la2, la3));
            *(uint2*)&xl_s[nxt][wi1] = make_uint2(pkbf2(lb0, lb1), pkbf2(lb2, lb3));
        }
        __syncthreads();
    }
}

// ---------------- launcher ----------------

extern "C" void kernel_launch(void* const* d_in, const int* in_sizes, int n_in,
                              void* d_out, int out_size, void* d_ws, size_t ws_size,
                              hipStream_t stream) {
    const float* y = (const float*)d_in[0];
    const float* A = (const float*)d_in[1];
    const float* H = (const float*)d_in[2];
    const float* K = (const float*)d_in[3];
    float* out = (float*)d_out;

    float* ws = (float*)d_ws;
    const long MAT = (long)NS * NS;  // 65536 floats
    float* KH = ws + 0 * MAT;
    float* AE = ws + 1 * MAT;
    float* Ta = ws + 2 * MAT;
    float* Tb = ws + 3 * MAT;
    float* M8 = ws + 4 * MAT;
    float* M64 = ws + 5 * MAT;
    ushort* aeh = (ushort*)(ws + 6 * MAT);
    ushort* ael = aeh + MAT;
    ushort* mh = (ushort*)(ws + 7 * MAT);
    ushort* ml = mh + MAT;
    ushort* m2h = (ushort*)(ws + 8 * MAT);
    ushort* m2l = m2h + MAT;
    ushort* kbh = (ushort*)(ws + 9 * MAT);
    ushort* kbl = kbh + (long)NS * MO;
    ushort* e_buf = (ushort*)(ws + 10 * MAT);  // [64][128][256] bf16 -> 16 MAT
    ushort* cbuf = (ushort*)(ws + 26 * MAT);   // [64][128][256] bf16 -> 16 MAT
    ushort* e2 = (ushort*)(ws + 42 * MAT);     // [64][16][256] bf16 -> 2 MAT
    ushort* c2 = (ushort*)(ws + 44 * MAT);     // [64][16][256] bf16 -> 2 MAT

    float* U = out;  // U = y@K^T lives in d_out; phase C overwrites in place

    kh_kernel<<<NS, NS, 0, stream>>>(K, H, KH, kbh, kbl);
    aeff_kernel<<<NS, NS, 0, stream>>>(A, KH, AE, aeh, ael);
    matsq_kernel<<<NS, NS, 0, stream>>>(AE, Ta, nullptr, nullptr);   // A^2
    matsq_kernel<<<NS, NS, 0, stream>>>(Ta, Tb, nullptr, nullptr);   // A^4
    matsq_kernel<<<NS, NS, 0, stream>>>(Tb, M8, mh, ml);             // A^8 (+conv)
    matsq_kernel<<<NS, NS, 0, stream>>>(M8, Ta, nullptr, nullptr);   // A^16
    matsq_kernel<<<NS, NS, 0, stream>>>(Ta, Tb, nullptr, nullptr);   // A^32
    matsq_kernel<<<NS, NS, 0, stream>>>(Tb, M64, m2h, m2l);          // A^64 (+conv)

    ugemm_kernel<<<512, 512, 0, stream>>>(y, kbh, kbl, U);

    scan16_kernel<0><<<512, 512, 0, stream>>>(aeh, ael, U, nullptr, nullptr, nullptr, nullptr, e_buf);
    scan16_kernel<1><<<64, 512, 0, stream>>>(mh, ml, nullptr, e_buf, nullptr, nullptr, nullptr, e2);
    scan16_kernel<2><<<4, 512, 0, stream>>>(m2h, m2l, nullptr, e2, nullptr, nullptr, c2, nullptr);
    scan16_kernel<3><<<64, 512, 0, stream>>>(mh, ml, nullptr, e_buf, c2, nullptr, cbuf, nullptr);
    scan16_kernel<4><<<512, 512, 0, stream>>>(aeh, ael, U, nullptr, cbuf, out, nullptr, nullptr);
}